// Round 2
// baseline (2934.246 us; speedup 1.0000x reference)
//
#include <hip/hip_runtime.h>

#define T_TOK 4096
#define H_DIM 2048
#define I_DIM 5632
#define NE 8

typedef _Float16 f16;
typedef _Float16 f16x8 __attribute__((ext_vector_type(8)));
typedef _Float16 f16x4 __attribute__((ext_vector_type(4)));
typedef float f32x4 __attribute__((ext_vector_type(4)));

// ---- workspace layout (byte offsets) ----
#define OFF_META   0                         // counts[8] | offs[8] | cursor[8]
#define OFF_BTOK   256
#define OFF_BW     (256 + 32768)
#define OFF_RE     (256 + 2 * 32768)
#define OFF_RW     (256 + 3 * 32768)
#define OFF_HSB    (256 + 4 * 32768)
#define OFF_HB     (OFF_HSB + (size_t)T_TOK * H_DIM * 2)

typedef const __attribute__((address_space(1))) unsigned int guint;
typedef __attribute__((address_space(3))) unsigned int luint;

#define WAITVM4()  asm volatile("s_waitcnt vmcnt(4)" ::: "memory")
#define WAITVM0()  asm volatile("s_waitcnt vmcnt(0)" ::: "memory")
#define WAITLG0()  asm volatile("s_waitcnt lgkmcnt(0)" ::: "memory")

// 8-slot (16B) XOR swizzle within a 128-byte LDS row: 2-way (free) ds_read_b128
__device__ __forceinline__ int swzk(int r, int bir) {
    return (bir & 15) | ((((bir >> 4) ^ r) & 7) << 4);
}

__device__ __forceinline__ f16x4 cvt4(float4 v) {
    f16x4 t; t[0] = (f16)v.x; t[1] = (f16)v.y; t[2] = (f16)v.z; t[3] = (f16)v.w; return t;
}

// ---------------- hs f32 -> f16 ----------------
__global__ void cvt_hs_kernel(const float* __restrict__ hs, f16* __restrict__ hsb) {
    size_t i = ((size_t)blockIdx.x * 256 + threadIdx.x) * 8;
    float4 a = *(const float4*)(hs + i);
    float4 b = *(const float4*)(hs + i + 4);
    f16x8 v;
    v[0] = (f16)a.x; v[1] = (f16)a.y; v[2] = (f16)a.z; v[3] = (f16)a.w;
    v[4] = (f16)b.x; v[5] = (f16)b.y; v[6] = (f16)b.z; v[7] = (f16)b.w;
    *(f16x8*)(hsb + i) = v;
}

// ---------------- gating ----------------
__global__ void gate_kernel(const float* __restrict__ hs, const float* __restrict__ gw,
                            int* __restrict__ re, float* __restrict__ rw,
                            int* __restrict__ counts) {
    int lane = threadIdx.x & 63;
    int t = blockIdx.x * 4 + (threadIdx.x >> 6);
    float acc[NE];
#pragma unroll
    for (int e = 0; e < NE; ++e) acc[e] = 0.f;
    const float* x = hs + (size_t)t * H_DIM;
    for (int i = lane; i < H_DIM; i += 64) {
        float xv = x[i];
#pragma unroll
        for (int e = 0; e < NE; ++e) acc[e] += xv * gw[e * H_DIM + i];
    }
#pragma unroll
    for (int e = 0; e < NE; ++e)
        for (int off = 32; off > 0; off >>= 1) acc[e] += __shfl_xor(acc[e], off);
    if (lane == 0) {
        int i1 = 0; float l1 = acc[0];
#pragma unroll
        for (int e = 1; e < NE; ++e) if (acc[e] > l1) { l1 = acc[e]; i1 = e; }
        int i2 = -1; float l2 = -1e30f;
#pragma unroll
        for (int e = 0; e < NE; ++e) if (e != i1 && acc[e] > l2) { l2 = acc[e]; i2 = e; }
        float aa = __expf(l2 - l1);
        float s = 1.f / (1.f + aa);
        re[t * 2] = i1; re[t * 2 + 1] = i2;
        rw[t * 2] = s;  rw[t * 2 + 1] = aa * s;
        atomicAdd(&counts[i1], 1);
        atomicAdd(&counts[i2], 1);
    }
}

__global__ void scan_kernel(int* __restrict__ meta) {
    if (threadIdx.x == 0) {
        int s = 0;
        for (int e = 0; e < NE; ++e) { meta[8 + e] = s; meta[16 + e] = s; s += meta[e]; }
    }
}

__global__ void place_kernel(const int* __restrict__ re, const float* __restrict__ rw,
                             int* __restrict__ cursor, int* __restrict__ btok,
                             float* __restrict__ bwv) {
    int t = blockIdx.x * 256 + threadIdx.x;
    if (t >= T_TOK) return;
#pragma unroll
    for (int s = 0; s < 2; ++s) {
        int e = re[t * 2 + s];
        int p = atomicAdd(&cursor[e], 1);
        btok[p] = t;
        bwv[p] = rw[t * 2 + s];
    }
}

// ---------------- GEMM1: h = silu(X@Wg^T) * (X@Wu^T) ----------------
// BM=256 tokens x 64 h-cols (g+u), BK=64, 512 thr / 8 waves (4m x 2n), wave 64x32x{g,u}.
// A: global_load_lds (pre-swizzled source); B: f32->f16 reg-staged, LDS double-buffered.
// Single s_barrier per K-tile with counted vmcnt (never 0 in loop).
__global__ __launch_bounds__(512, 2) void gemm1_kernel(
    const float* __restrict__ w13, const f16* __restrict__ hsb, f16* __restrict__ hb,
    const int* __restrict__ counts, const int* __restrict__ offs,
    const int* __restrict__ btok, int e_arg, int global_h)
{
    // XCD-chunked decode: consecutive logical ids (same e,bx; different by) share one XCD's L2
    const int nwg = gridDim.x;
    const int cpx = nwg >> 3;
    const int lin = blockIdx.x;
    const int logical = (lin & 7) * cpx + (lin >> 3);
    const int by = logical & 15;
    const int rest = logical >> 4;
    int bx, e;
    if (e_arg >= 0) { bx = rest; e = e_arg; }
    else            { bx = rest % 88; e = rest / 88; }

    const int n_e = counts[e];
    if (by * 256 >= n_e) return;
    const int boff = offs[e];
    const float* We = w13 + (size_t)e * (2 * I_DIM) * H_DIM;

    const int tid = threadIdx.x;
    const int lane = tid & 63;
    const int wid = tid >> 6;
    const int wm = wid >> 1, wn = wid & 1;

    __shared__ f16 As[2][256 * 64];   // 32768 B per buffer
    __shared__ f16 Bg[2][64 * 64];    // 8192 B per buffer
    __shared__ f16 Bu[2][64 * 64];
    char* AsB = (char*)As;
    char* BgB = (char*)Bg;
    char* BuB = (char*)Bu;

    // A gather sources for global_load_lds: group c = wid*4+i covers rows c*8..c*8+7.
    // lane j -> row r = c*8 + (j>>3), LDS slot j&7, global slot (j&7)^(j>>3)  (inverse swizzle)
    const f16* gA[4];
    int cgrp[4];
#pragma unroll
    for (int i = 0; i < 4; ++i) {
        int c = wid * 4 + i;
        cgrp[i] = c;
        int r = c * 8 + (lane >> 3);
        int idx = by * 256 + r;
        idx = idx < n_e ? idx : n_e - 1;
        int tok = btok[boff + idx];
        int sg = (lane & 7) ^ (lane >> 3);
        gA[i] = hsb + (size_t)tok * H_DIM + sg * 8;
    }
    // B sources: chunk c = j*512+tid -> row c>>4 (0..63), f32-quad (c&15)
    const float* gBg[2]; const float* gBu[2];
    int bwadr[2];
#pragma unroll
    for (int j = 0; j < 2; ++j) {
        int c = j * 512 + tid;
        int r = c >> 4;
        int k4 = c & 15;
        gBg[j] = We + (size_t)(bx * 64 + r) * H_DIM + k4 * 4;
        gBu[j] = We + (size_t)(I_DIM + bx * 64 + r) * H_DIM + k4 * 4;
        bwadr[j] = r * 128 + swzk(r, k4 * 8);
    }

    f32x4 accg[4][2], accu[4][2];
#pragma unroll
    for (int m = 0; m < 4; ++m)
#pragma unroll
        for (int n = 0; n < 2; ++n) { accg[m][n] = (f32x4)0.f; accu[m][n] = (f32x4)0.f; }

    const int NT = H_DIM / 64;   // 32

    // prologue: B[0] -> LDS buf0 (compiler drains these loads); then issue A[0]
    {
        float4 g0 = *(const float4*)gBg[0];
        float4 g1 = *(const float4*)gBg[1];
        float4 u0 = *(const float4*)gBu[0];
        float4 u1 = *(const float4*)gBu[1];
        *(f16x4*)(BgB + bwadr[0]) = cvt4(g0);
        *(f16x4*)(BgB + bwadr[1]) = cvt4(g1);
        *(f16x4*)(BuB + bwadr[0]) = cvt4(u0);
        *(f16x4*)(BuB + bwadr[1]) = cvt4(u1);
#pragma unroll
        for (int i = 0; i < 4; ++i)
            __builtin_amdgcn_global_load_lds((guint*)(gA[i]), (luint*)(AsB + cgrp[i] * 1024), 16, 0, 0);
    }

    int cur = 0;
#pragma unroll 1
    for (int kt = 0; kt < NT; ++kt) {
        const int ktn = (kt + 1 < NT) ? kt + 1 : NT - 1;
        // prefetch next B tile into regs (stays in flight across the barrier)
        float4 g0 = *(const float4*)(gBg[0] + ktn * 64);
        float4 g1 = *(const float4*)(gBg[1] + ktn * 64);
        float4 u0 = *(const float4*)(gBu[0] + ktn * 64);
        float4 u1 = *(const float4*)(gBu[1] + ktn * 64);
        WAITVM4();    // my A[kt] gload_lds landed (B[kt+1] still flying)
        WAITLG0();    // my B[kt] ds_writes visible
        __builtin_amdgcn_s_barrier();
        __builtin_amdgcn_sched_barrier(0);
        // issue A[kt+1] into the other buffer (all waves finished reading it)
#pragma unroll
        for (int i = 0; i < 4; ++i)
            __builtin_amdgcn_global_load_lds((guint*)(gA[i] + ktn * 64),
                (luint*)(AsB + (cur ^ 1) * 32768 + cgrp[i] * 1024), 16, 0, 0);
        // compute on buffer cur
        const char* Ab = AsB + cur * 32768;
        const char* Gb = BgB + cur * 8192;
        const char* Ub = BuB + cur * 8192;
#pragma unroll
        for (int kh = 0; kh < 2; ++kh) {
            f16x8 a[4], bg[2], bu[2];
            const int kb = kh * 64 + (lane >> 4) * 16;
#pragma unroll
            for (int m = 0; m < 4; ++m) {
                int r = wm * 64 + m * 16 + (lane & 15);
                a[m] = *(const f16x8*)(Ab + r * 128 + swzk(r, kb));
            }
#pragma unroll
            for (int n = 0; n < 2; ++n) {
                int r = wn * 32 + n * 16 + (lane & 15);
                bg[n] = *(const f16x8*)(Gb + r * 128 + swzk(r, kb));
                bu[n] = *(const f16x8*)(Ub + r * 128 + swzk(r, kb));
            }
#pragma unroll
            for (int m = 0; m < 4; ++m)
#pragma unroll
                for (int n = 0; n < 2; ++n) {
                    accg[m][n] = __builtin_amdgcn_mfma_f32_16x16x32_f16(a[m], bg[n], accg[m][n], 0, 0, 0);
                    accu[m][n] = __builtin_amdgcn_mfma_f32_16x16x32_f16(a[m], bu[n], accu[m][n], 0, 0, 0);
                }
        }
        // B[kt+1] regs arrived by now (hidden under MFMAs); A[kt+1] still flying
        WAITVM4();
        {
            char* Gn = BgB + (cur ^ 1) * 8192;
            char* Un = BuB + (cur ^ 1) * 8192;
            *(f16x4*)(Gn + bwadr[0]) = cvt4(g0);
            *(f16x4*)(Gn + bwadr[1]) = cvt4(g1);
            *(f16x4*)(Un + bwadr[0]) = cvt4(u0);
            *(f16x4*)(Un + bwadr[1]) = cvt4(u1);
        }
        cur ^= 1;
    }
    WAITVM0();   // drain pending gload_lds before LDS dealloc

    // epilogue: silu(g)*u -> f16 h
    const int hbase = (global_h ? boff : 0) + by * 256;
#pragma unroll
    for (int m = 0; m < 4; ++m) {
        int rl0 = wm * 64 + m * 16 + ((lane >> 4) << 2);
#pragma unroll
        for (int r = 0; r < 4; ++r) {
            int rl = rl0 + r;
            if (by * 256 + rl < n_e) {
#pragma unroll
                for (int n = 0; n < 2; ++n) {
                    float g = accg[m][n][r];
                    float u = accu[m][n][r];
                    float h = g / (1.f + __expf(-g)) * u;
                    hb[(size_t)(hbase + rl) * I_DIM + bx * 64 + wn * 32 + n * 16 + (lane & 15)] = (f16)h;
                }
            }
        }
    }
}

// ---------------- GEMM2: out[tok] += w * (h @ w2^T) ----------------
// BM=256 x BN=128, BK=64, 512 thr / 8 waves (4m x 2n), wave 64x64. Same pipeline as gemm1.
__global__ __launch_bounds__(512, 2) void gemm2_kernel(
    const float* __restrict__ w2, const f16* __restrict__ hb, float* __restrict__ out,
    const int* __restrict__ counts, const int* __restrict__ offs,
    const int* __restrict__ btok, const float* __restrict__ bwv, int e_arg, int global_h)
{
    const int nwg = gridDim.x;
    const int cpx = nwg >> 3;
    const int lin = blockIdx.x;
    const int logical = (lin & 7) * cpx + (lin >> 3);
    const int by = logical & 15;
    const int rest = logical >> 4;
    int bx, e;
    if (e_arg >= 0) { bx = rest; e = e_arg; }
    else            { bx = rest % 16; e = rest / 16; }

    const int n_e = counts[e];
    if (by * 256 >= n_e) return;
    const int boff = offs[e];
    const float* We = w2 + (size_t)e * H_DIM * I_DIM;

    const int tid = threadIdx.x;
    const int lane = tid & 63;
    const int wid = tid >> 6;
    const int wm = wid >> 1, wn = wid & 1;

    __shared__ f16 As[2][256 * 64];   // 32768 B per buffer
    __shared__ f16 Bs[2][128 * 64];   // 16384 B per buffer
    char* AsB = (char*)As;
    char* BsB = (char*)Bs;

    const int hbase = (global_h ? boff : 0) + by * 256;
    const f16* gA[4];
    int cgrp[4];
#pragma unroll
    for (int i = 0; i < 4; ++i) {
        int c = wid * 4 + i;
        cgrp[i] = c;
        int r = c * 8 + (lane >> 3);
        int sg = (lane & 7) ^ (lane >> 3);
        gA[i] = hb + (size_t)(hbase + r) * I_DIM + sg * 8;
    }
    const float* gB[4];
    int bwadr[4];
#pragma unroll
    for (int j = 0; j < 4; ++j) {
        int c = j * 512 + tid;
        int r = c >> 4;          // 0..127
        int k4 = c & 15;
        gB[j] = We + (size_t)(bx * 128 + r) * I_DIM + k4 * 4;
        bwadr[j] = r * 128 + swzk(r, k4 * 8);
    }

    f32x4 acc[4][4];
#pragma unroll
    for (int m = 0; m < 4; ++m)
#pragma unroll
        for (int n = 0; n < 4; ++n) acc[m][n] = (f32x4)0.f;

    const int NT = I_DIM / 64;   // 88

    {
        float4 b0 = *(const float4*)gB[0];
        float4 b1 = *(const float4*)gB[1];
        float4 b2 = *(const float4*)gB[2];
        float4 b3 = *(const float4*)gB[3];
        *(f16x4*)(BsB + bwadr[0]) = cvt4(b0);
        *(f16x4*)(BsB + bwadr[1]) = cvt4(b1);
        *(f16x4*)(BsB + bwadr[2]) = cvt4(b2);
        *(f16x4*)(BsB + bwadr[3]) = cvt4(b3);
#pragma unroll
        for (int i = 0; i < 4; ++i)
            __builtin_amdgcn_global_load_lds((guint*)(gA[i]), (luint*)(AsB + cgrp[i] * 1024), 16, 0, 0);
    }

    int cur = 0;
#pragma unroll 1
    for (int kt = 0; kt < NT; ++kt) {
        const int ktn = (kt + 1 < NT) ? kt + 1 : NT - 1;
        float4 b0 = *(const float4*)(gB[0] + ktn * 64);
        float4 b1 = *(const float4*)(gB[1] + ktn * 64);
        float4 b2 = *(const float4*)(gB[2] + ktn * 64);
        float4 b3 = *(const float4*)(gB[3] + ktn * 64);
        WAITVM4();
        WAITLG0();
        __builtin_amdgcn_s_barrier();
        __builtin_amdgcn_sched_barrier(0);
#pragma unroll
        for (int i = 0; i < 4; ++i)
            __builtin_amdgcn_global_load_lds((guint*)(gA[i] + ktn * 64),
                (luint*)(AsB + (cur ^ 1) * 32768 + cgrp[i] * 1024), 16, 0, 0);
        const char* Ab = AsB + cur * 32768;
        const char* Bb = BsB + cur * 16384;
#pragma unroll
        for (int kh = 0; kh < 2; ++kh) {
            f16x8 a[4], b[4];
            const int kb = kh * 64 + (lane >> 4) * 16;
#pragma unroll
            for (int m = 0; m < 4; ++m) {
                int r = wm * 64 + m * 16 + (lane & 15);
                a[m] = *(const f16x8*)(Ab + r * 128 + swzk(r, kb));
            }
#pragma unroll
            for (int n = 0; n < 4; ++n) {
                int r = wn * 64 + n * 16 + (lane & 15);
                b[n] = *(const f16x8*)(Bb + r * 128 + swzk(r, kb));
            }
#pragma unroll
            for (int m = 0; m < 4; ++m)
#pragma unroll
                for (int n = 0; n < 4; ++n)
                    acc[m][n] = __builtin_amdgcn_mfma_f32_16x16x32_f16(a[m], b[n], acc[m][n], 0, 0, 0);
        }
        WAITVM4();
        {
            char* Bn = BsB + (cur ^ 1) * 16384;
            *(f16x4*)(Bn + bwadr[0]) = cvt4(b0);
            *(f16x4*)(Bn + bwadr[1]) = cvt4(b1);
            *(f16x4*)(Bn + bwadr[2]) = cvt4(b2);
            *(f16x4*)(Bn + bwadr[3]) = cvt4(b3);
        }
        cur ^= 1;
    }
    WAITVM0();

    // epilogue: weighted scatter-add
#pragma unroll
    for (int m = 0; m < 4; ++m) {
        int rl0 = wm * 64 + m * 16 + ((lane >> 4) << 2);
#pragma unroll
        for (int r = 0; r < 4; ++r) {
            int rl = rl0 + r;
            if (by * 256 + rl < n_e) {
                int p = boff + by * 256 + rl;
                int tok = btok[p];
                float w = bwv[p];
#pragma unroll
                for (int n = 0; n < 4; ++n)
                    atomicAdd(&out[(size_t)tok * H_DIM + bx * 128 + wn * 64 + n * 16 + (lane & 15)],
                              w * acc[m][n][r]);
            }
        }
    }
}

extern "C" void kernel_launch(void* const* d_in, const int* in_sizes, int n_in,
                              void* d_out, int out_size, void* d_ws, size_t ws_size,
                              hipStream_t stream) {
    const float* hs  = (const float*)d_in[0];
    const float* gw  = (const float*)d_in[1];
    const float* w13 = (const float*)d_in[2];
    const float* w2  = (const float*)d_in[3];
    float* out = (float*)d_out;

    char* ws = (char*)d_ws;
    int*   meta = (int*)(ws + OFF_META);
    int*   btok = (int*)(ws + OFF_BTOK);
    float* bwv  = (float*)(ws + OFF_BW);
    int*   re   = (int*)(ws + OFF_RE);
    float* rw   = (float*)(ws + OFF_RW);
    f16*   hsb  = (f16*)(ws + OFF_HSB);
    f16*   hb   = (f16*)(ws + OFF_HB);

    hipMemsetAsync(d_out, 0, (size_t)T_TOK * H_DIM * 4, stream);
    hipMemsetAsync(meta, 0, 256, stream);

    cvt_hs_kernel<<<(T_TOK * H_DIM) / (256 * 8), 256, 0, stream>>>(hs, hsb);
    gate_kernel<<<T_TOK / 4, 256, 0, stream>>>(hs, gw, re, rw, meta);
    scan_kernel<<<1, 64, 0, stream>>>(meta);
    place_kernel<<<T_TOK / 256, 256, 0, stream>>>(re, rw, meta + 16, btok, bwv);

    size_t need_allpairs = OFF_HB + (size_t)(2 * T_TOK + 256) * I_DIM * 2;
    if (ws_size >= need_allpairs) {
        gemm1_kernel<<<16 * 88 * NE, 512, 0, stream>>>(w13, hsb, hb, meta, meta + 8, btok, -1, 1);
        gemm2_kernel<<<16 * 16 * NE, 512, 0, stream>>>(w2, hb, out, meta, meta + 8, btok, bwv, -1, 1);
    } else {
        for (int e = 0; e < NE; ++e) {
            gemm1_kernel<<<16 * 88, 512, 0, stream>>>(w13, hsb, hb, meta, meta + 8, btok, e, 0);
            gemm2_kernel<<<16 * 16, 512, 0, stream>>>(w2, hb, out, meta, meta + 8, btok, bwv, e, 0);
        }
    }
}

// Round 3
// 1578.775 us; speedup vs baseline: 1.8586x; 1.8586x over previous
//
#include <hip/hip_runtime.h>

#define T_TOK 4096
#define H_DIM 2048
#define I_DIM 5632
#define NE 8

typedef _Float16 f16;
typedef _Float16 f16x8 __attribute__((ext_vector_type(8)));
typedef _Float16 f16x4 __attribute__((ext_vector_type(4)));
typedef float f32x4 __attribute__((ext_vector_type(4)));

// ---- workspace layout (byte offsets) ----
#define OFF_META   0                         // counts[8] | offs[8] | cursor[8]
#define OFF_BTOK   256
#define OFF_BW     (256 + 32768)
#define OFF_RE     (256 + 2 * 32768)
#define OFF_RW     (256 + 3 * 32768)
#define OFF_HSB    (256 + 4 * 32768)
#define OFF_HB     (OFF_HSB + (size_t)T_TOK * H_DIM * 2)

// 8-slot (16B) XOR swizzle within a 128-byte LDS row: 2-way (free) ds_read_b128
__device__ __forceinline__ int swzk(int r, int bir) {
    return (bir & 15) | ((((bir >> 4) ^ r) & 7) << 4);
}

__device__ __forceinline__ f16x4 cvt4(float4 v) {
    f16x4 t; t[0] = (f16)v.x; t[1] = (f16)v.y; t[2] = (f16)v.z; t[3] = (f16)v.w; return t;
}

// ---------------- hs f32 -> f16 ----------------
__global__ void cvt_hs_kernel(const float* __restrict__ hs, f16* __restrict__ hsb) {
    size_t i = ((size_t)blockIdx.x * 256 + threadIdx.x) * 8;
    float4 a = *(const float4*)(hs + i);
    float4 b = *(const float4*)(hs + i + 4);
    f16x8 v;
    v[0] = (f16)a.x; v[1] = (f16)a.y; v[2] = (f16)a.z; v[3] = (f16)a.w;
    v[4] = (f16)b.x; v[5] = (f16)b.y; v[6] = (f16)b.z; v[7] = (f16)b.w;
    *(f16x8*)(hsb + i) = v;
}

// ---------------- gating ----------------
__global__ void gate_kernel(const float* __restrict__ hs, const float* __restrict__ gw,
                            int* __restrict__ re, float* __restrict__ rw,
                            int* __restrict__ counts) {
    int lane = threadIdx.x & 63;
    int t = blockIdx.x * 4 + (threadIdx.x >> 6);
    float acc[NE];
#pragma unroll
    for (int e = 0; e < NE; ++e) acc[e] = 0.f;
    const float* x = hs + (size_t)t * H_DIM;
    for (int i = lane; i < H_DIM; i += 64) {
        float xv = x[i];
#pragma unroll
        for (int e = 0; e < NE; ++e) acc[e] += xv * gw[e * H_DIM + i];
    }
#pragma unroll
    for (int e = 0; e < NE; ++e)
        for (int off = 32; off > 0; off >>= 1) acc[e] += __shfl_xor(acc[e], off);
    if (lane == 0) {
        int i1 = 0; float l1 = acc[0];
#pragma unroll
        for (int e = 1; e < NE; ++e) if (acc[e] > l1) { l1 = acc[e]; i1 = e; }
        int i2 = -1; float l2 = -1e30f;
#pragma unroll
        for (int e = 0; e < NE; ++e) if (e != i1 && acc[e] > l2) { l2 = acc[e]; i2 = e; }
        float aa = __expf(l2 - l1);
        float s = 1.f / (1.f + aa);
        re[t * 2] = i1; re[t * 2 + 1] = i2;
        rw[t * 2] = s;  rw[t * 2 + 1] = aa * s;
        atomicAdd(&counts[i1], 1);
        atomicAdd(&counts[i2], 1);
    }
}

__global__ void scan_kernel(int* __restrict__ meta) {
    if (threadIdx.x == 0) {
        int s = 0;
        for (int e = 0; e < NE; ++e) { meta[8 + e] = s; meta[16 + e] = s; s += meta[e]; }
    }
}

__global__ void place_kernel(const int* __restrict__ re, const float* __restrict__ rw,
                             int* __restrict__ cursor, int* __restrict__ btok,
                             float* __restrict__ bwv) {
    int t = blockIdx.x * 256 + threadIdx.x;
    if (t >= T_TOK) return;
#pragma unroll
    for (int s = 0; s < 2; ++s) {
        int e = re[t * 2 + s];
        int p = atomicAdd(&cursor[e], 1);
        btok[p] = t;
        bwv[p] = rw[t * 2 + s];
    }
}

// Panel-pinned XCD decode: panel P = sg*8 + (id&7) stays on XCD id%8; the
// (up to 32) by-blocks of one panel are contiguous ids on that XCD.
// Returns false for inactive (by*128 >= n_e handled by caller).
__device__ __forceinline__ void decode_panel(int id, int npx, int e_arg,
                                             int& e, int& bx, int& by) {
    int sg  = id >> 8;          // super-group: 8 panels x 32 by = 256 blocks
    int rem = id & 255;
    by = rem >> 3;
    int P = sg * 8 + (rem & 7);
    if (e_arg >= 0) { e = e_arg; bx = P; }
    else            { e = P / npx; bx = P % npx; }
}

// ---------------- GEMM1: h = silu(X@Wg^T) * (X@Wu^T) ----------------
// BM=128 tokens x 64 h-cols (g+u pair), BK=64, 256 thr / 4 waves (2x2),
// wave = 64 rows x 32 cols of both g and u. Single-buffer LDS, reg prefetch.
__global__ __launch_bounds__(256) void gemm1_kernel(
    const float* __restrict__ w13, const f16* __restrict__ hsb, f16* __restrict__ hb,
    const int* __restrict__ counts, const int* __restrict__ offs,
    const int* __restrict__ btok, int e_arg, int global_h)
{
    int e, bx, by;
    decode_panel(blockIdx.x, 88, e_arg, e, bx, by);
    const int n_e = counts[e];
    if (by * 128 >= n_e) return;
    const int boff = offs[e];
    const float* We = w13 + (size_t)e * (2 * I_DIM) * H_DIM;

    const int tid = threadIdx.x;
    const int lane = tid & 63;
    const int wid = tid >> 6;
    const int wm = wid >> 1, wn = wid & 1;

    __shared__ f16 As[128 * 64];   // 16 KB, 128B rows
    __shared__ f16 Bg[64 * 64];    // 8 KB
    __shared__ f16 Bu[64 * 64];    // 8 KB
    char* AsB = (char*)As; char* BgB = (char*)Bg; char* BuB = (char*)Bu;

    // A: 4 chunks of 16B per thread. chunk c = i*256+tid: row c>>3, slot c&7
    const f16* gA[4];
    int awadr[4];
#pragma unroll
    for (int i = 0; i < 4; ++i) {
        int c = i * 256 + tid;
        int r = c >> 3;
        int s = c & 7;
        int idx = by * 128 + r;
        idx = idx < n_e ? idx : n_e - 1;
        int tok = btok[boff + idx];
        gA[i] = hsb + (size_t)tok * H_DIM + s * 8;
        awadr[i] = r * 128 + swzk(r, s * 16);
    }
    // B: per matrix 4 float4/thread. chunk c = j*256+tid: row c>>4, quad c&15
    const float* gBg[4]; const float* gBu[4];
    int bwadr[4];
#pragma unroll
    for (int j = 0; j < 4; ++j) {
        int c = j * 256 + tid;
        int r = c >> 4;
        int k4 = c & 15;
        gBg[j] = We + (size_t)(bx * 64 + r) * H_DIM + k4 * 4;
        gBu[j] = We + (size_t)(I_DIM + bx * 64 + r) * H_DIM + k4 * 4;
        bwadr[j] = r * 128 + swzk(r, k4 * 8);
    }

    f32x4 accg[4][2], accu[4][2];
#pragma unroll
    for (int m = 0; m < 4; ++m)
#pragma unroll
        for (int n = 0; n < 2; ++n) { accg[m][n] = (f32x4)0.f; accu[m][n] = (f32x4)0.f; }

    const int NT = H_DIM / 64;   // 32

    f16x8 aR[4]; float4 gR[4], uR[4];
#pragma unroll
    for (int i = 0; i < 4; ++i) {
        aR[i] = *(const f16x8*)(gA[i]);
        gR[i] = *(const float4*)(gBg[i]);
        uR[i] = *(const float4*)(gBu[i]);
    }

#pragma unroll 1
    for (int kt = 0; kt < NT; ++kt) {
        __syncthreads();
#pragma unroll
        for (int i = 0; i < 4; ++i) {
            *(f16x8*)(AsB + awadr[i]) = aR[i];
            *(f16x4*)(BgB + bwadr[i]) = cvt4(gR[i]);
            *(f16x4*)(BuB + bwadr[i]) = cvt4(uR[i]);
        }
        __syncthreads();
        if (kt + 1 < NT) {
            int k0 = (kt + 1) * 64;
#pragma unroll
            for (int i = 0; i < 4; ++i) {
                aR[i] = *(const f16x8*)(gA[i] + k0);
                gR[i] = *(const float4*)(gBg[i] + k0);
                uR[i] = *(const float4*)(gBu[i] + k0);
            }
        }
#pragma unroll
        for (int kh = 0; kh < 2; ++kh) {
            f16x8 a[4], bg[2], bu[2];
            const int kb = kh * 64 + (lane >> 4) * 16;
#pragma unroll
            for (int m = 0; m < 4; ++m) {
                int r = wm * 64 + m * 16 + (lane & 15);
                a[m] = *(const f16x8*)(AsB + r * 128 + swzk(r, kb));
            }
#pragma unroll
            for (int n = 0; n < 2; ++n) {
                int r = wn * 32 + n * 16 + (lane & 15);
                bg[n] = *(const f16x8*)(BgB + r * 128 + swzk(r, kb));
                bu[n] = *(const f16x8*)(BuB + r * 128 + swzk(r, kb));
            }
#pragma unroll
            for (int m = 0; m < 4; ++m)
#pragma unroll
                for (int n = 0; n < 2; ++n) {
                    accg[m][n] = __builtin_amdgcn_mfma_f32_16x16x32_f16(a[m], bg[n], accg[m][n], 0, 0, 0);
                    accu[m][n] = __builtin_amdgcn_mfma_f32_16x16x32_f16(a[m], bu[n], accu[m][n], 0, 0, 0);
                }
        }
    }

    // epilogue: silu(g)*u -> f16 h
    const int hbase = (global_h ? boff : 0) + by * 128;
#pragma unroll
    for (int m = 0; m < 4; ++m) {
        int rl0 = wm * 64 + m * 16 + ((lane >> 4) << 2);
#pragma unroll
        for (int r = 0; r < 4; ++r) {
            int rl = rl0 + r;
            if (by * 128 + rl < n_e) {
#pragma unroll
                for (int n = 0; n < 2; ++n) {
                    float g = accg[m][n][r];
                    float u = accu[m][n][r];
                    float h = g / (1.f + __expf(-g)) * u;
                    hb[(size_t)(hbase + rl) * I_DIM + bx * 64 + wn * 32 + n * 16 + (lane & 15)] = (f16)h;
                }
            }
        }
    }
}

// ---------------- GEMM2: out[tok] += w * (h @ w2^T) ----------------
// BM=128 x BN=128, BK=64, 256 thr / 4 waves (2x2), wave 64x64.
__global__ __launch_bounds__(256) void gemm2_kernel(
    const float* __restrict__ w2, const f16* __restrict__ hb, float* __restrict__ out,
    const int* __restrict__ counts, const int* __restrict__ offs,
    const int* __restrict__ btok, const float* __restrict__ bwv, int e_arg, int global_h)
{
    int e, bx, by;
    decode_panel(blockIdx.x, 16, e_arg, e, bx, by);
    const int n_e = counts[e];
    if (by * 128 >= n_e) return;
    const int boff = offs[e];
    const float* We = w2 + (size_t)e * H_DIM * I_DIM;

    const int tid = threadIdx.x;
    const int lane = tid & 63;
    const int wid = tid >> 6;
    const int wm = wid >> 1, wn = wid & 1;

    __shared__ f16 As[128 * 64];   // 16 KB
    __shared__ f16 Bs[128 * 64];   // 16 KB
    char* AsB = (char*)As; char* BsB = (char*)Bs;

    const int hbase = (global_h ? boff : 0) + by * 128;
    const f16* gA[4];
    int awadr[4];
#pragma unroll
    for (int i = 0; i < 4; ++i) {
        int c = i * 256 + tid;
        int r = c >> 3;
        int s = c & 7;
        gA[i] = hb + (size_t)(hbase + r) * I_DIM + s * 8;
        awadr[i] = r * 128 + swzk(r, s * 16);
    }
    const float* gB[8];
    int bwadr[8];
#pragma unroll
    for (int j = 0; j < 8; ++j) {
        int c = j * 256 + tid;
        int r = c >> 4;          // 0..127
        int k4 = c & 15;
        gB[j] = We + (size_t)(bx * 128 + r) * I_DIM + k4 * 4;
        bwadr[j] = r * 128 + swzk(r, k4 * 8);
    }

    f32x4 acc[4][4];
#pragma unroll
    for (int m = 0; m < 4; ++m)
#pragma unroll
        for (int n = 0; n < 4; ++n) acc[m][n] = (f32x4)0.f;

    const int NT = I_DIM / 64;   // 88

    f16x8 aR[4]; float4 bR[8];
#pragma unroll
    for (int i = 0; i < 4; ++i) aR[i] = *(const f16x8*)(gA[i]);
#pragma unroll
    for (int j = 0; j < 8; ++j) bR[j] = *(const float4*)(gB[j]);

#pragma unroll 1
    for (int kt = 0; kt < NT; ++kt) {
        __syncthreads();
#pragma unroll
        for (int i = 0; i < 4; ++i) *(f16x8*)(AsB + awadr[i]) = aR[i];
#pragma unroll
        for (int j = 0; j < 8; ++j) *(f16x4*)(BsB + bwadr[j]) = cvt4(bR[j]);
        __syncthreads();
        if (kt + 1 < NT) {
            int k0 = (kt + 1) * 64;
#pragma unroll
            for (int i = 0; i < 4; ++i) aR[i] = *(const f16x8*)(gA[i] + k0);
#pragma unroll
            for (int j = 0; j < 8; ++j) bR[j] = *(const float4*)(gB[j] + k0);
        }
#pragma unroll
        for (int kh = 0; kh < 2; ++kh) {
            f16x8 a[4], b[4];
            const int kb = kh * 64 + (lane >> 4) * 16;
#pragma unroll
            for (int m = 0; m < 4; ++m) {
                int r = wm * 64 + m * 16 + (lane & 15);
                a[m] = *(const f16x8*)(AsB + r * 128 + swzk(r, kb));
            }
#pragma unroll
            for (int n = 0; n < 4; ++n) {
                int r = wn * 64 + n * 16 + (lane & 15);
                b[n] = *(const f16x8*)(BsB + r * 128 + swzk(r, kb));
            }
#pragma unroll
            for (int m = 0; m < 4; ++m)
#pragma unroll
                for (int n = 0; n < 4; ++n)
                    acc[m][n] = __builtin_amdgcn_mfma_f32_16x16x32_f16(a[m], b[n], acc[m][n], 0, 0, 0);
        }
    }

    // epilogue: weighted scatter-add
#pragma unroll
    for (int m = 0; m < 4; ++m) {
        int rl0 = wm * 64 + m * 16 + ((lane >> 4) << 2);
#pragma unroll
        for (int r = 0; r < 4; ++r) {
            int rl = rl0 + r;
            if (by * 128 + rl < n_e) {
                int p = boff + by * 128 + rl;
                int tok = btok[p];
                float w = bwv[p];
#pragma unroll
                for (int n = 0; n < 4; ++n)
                    atomicAdd(&out[(size_t)tok * H_DIM + bx * 128 + wn * 64 + n * 16 + (lane & 15)],
                              w * acc[m][n][r]);
            }
        }
    }
}

extern "C" void kernel_launch(void* const* d_in, const int* in_sizes, int n_in,
                              void* d_out, int out_size, void* d_ws, size_t ws_size,
                              hipStream_t stream) {
    const float* hs  = (const float*)d_in[0];
    const float* gw  = (const float*)d_in[1];
    const float* w13 = (const float*)d_in[2];
    const float* w2  = (const float*)d_in[3];
    float* out = (float*)d_out;

    char* ws = (char*)d_ws;
    int*   meta = (int*)(ws + OFF_META);
    int*   btok = (int*)(ws + OFF_BTOK);
    float* bwv  = (float*)(ws + OFF_BW);
    int*   re   = (int*)(ws + OFF_RE);
    float* rw   = (float*)(ws + OFF_RW);
    f16*   hsb  = (f16*)(ws + OFF_HSB);
    f16*   hb   = (f16*)(ws + OFF_HB);

    hipMemsetAsync(d_out, 0, (size_t)T_TOK * H_DIM * 4, stream);
    hipMemsetAsync(meta, 0, 256, stream);

    cvt_hs_kernel<<<(T_TOK * H_DIM) / (256 * 8), 256, 0, stream>>>(hs, hsb);
    gate_kernel<<<T_TOK / 4, 256, 0, stream>>>(hs, gw, re, rw, meta);
    scan_kernel<<<1, 64, 0, stream>>>(meta);
    place_kernel<<<T_TOK / 256, 256, 0, stream>>>(re, rw, meta + 16, btok, bwv);

    size_t need_allpairs = OFF_HB + (size_t)(2 * T_TOK + 128) * I_DIM * 2;
    if (ws_size >= need_allpairs) {
        // panels: gemm1 = 8*88 = 704, gemm2 = 8*16 = 128; 32 by-blocks per panel
        gemm1_kernel<<<704 * 32, 256, 0, stream>>>(w13, hsb, hb, meta, meta + 8, btok, -1, 1);
        gemm2_kernel<<<128 * 32, 256, 0, stream>>>(w2, hb, out, meta, meta + 8, btok, bwv, -1, 1);
    } else {
        for (int e = 0; e < NE; ++e) {
            gemm1_kernel<<<88 * 32, 256, 0, stream>>>(w13, hsb, hb, meta, meta + 8, btok, e, 0);
            gemm2_kernel<<<16 * 32, 256, 0, stream>>>(w2, hb, out, meta, meta + 8, btok, bwv, e, 0);
        }
    }
}

// Round 4
// 1151.804 us; speedup vs baseline: 2.5475x; 1.3707x over previous
//
#include <hip/hip_runtime.h>

#define T_TOK 4096
#define H_DIM 2048
#define I_DIM 5632
#define NE 8

typedef _Float16 f16;
typedef _Float16 f16x8 __attribute__((ext_vector_type(8)));
typedef _Float16 f16x4 __attribute__((ext_vector_type(4)));
typedef float f32x4 __attribute__((ext_vector_type(4)));

// ---- workspace layout (byte offsets) ----
#define OFF_META   0                         // counts[8] | offs[8] | cursor[8]
#define OFF_BTOK   256
#define OFF_BW     (256 + 32768)
#define OFF_RE     (256 + 2 * 32768)
#define OFF_RW     (256 + 3 * 32768)
#define OFF_HSB    (256 + 4 * 32768)
#define OFF_HB     (OFF_HSB + (size_t)T_TOK * H_DIM * 2)

// 8-slot (16B) XOR swizzle within a 128-byte LDS row: conflict-free (verified R3: 0 conflicts)
__device__ __forceinline__ int swzk(int r, int bir) {
    return (bir & 15) | ((((bir >> 4) ^ r) & 7) << 4);
}

__device__ __forceinline__ f16x4 cvt4(float4 v) {
    f16x4 t; t[0] = (f16)v.x; t[1] = (f16)v.y; t[2] = (f16)v.z; t[3] = (f16)v.w; return t;
}

// ---------------- hs f32 -> f16 ----------------
__global__ void cvt_hs_kernel(const float* __restrict__ hs, f16* __restrict__ hsb) {
    size_t i = ((size_t)blockIdx.x * 256 + threadIdx.x) * 8;
    float4 a = *(const float4*)(hs + i);
    float4 b = *(const float4*)(hs + i + 4);
    f16x8 v;
    v[0] = (f16)a.x; v[1] = (f16)a.y; v[2] = (f16)a.z; v[3] = (f16)a.w;
    v[4] = (f16)b.x; v[5] = (f16)b.y; v[6] = (f16)b.z; v[7] = (f16)b.w;
    *(f16x8*)(hsb + i) = v;
}

// ---------------- gating ----------------
__global__ void gate_kernel(const float* __restrict__ hs, const float* __restrict__ gw,
                            int* __restrict__ re, float* __restrict__ rw,
                            int* __restrict__ counts) {
    int lane = threadIdx.x & 63;
    int t = blockIdx.x * 4 + (threadIdx.x >> 6);
    float acc[NE];
#pragma unroll
    for (int e = 0; e < NE; ++e) acc[e] = 0.f;
    const float* x = hs + (size_t)t * H_DIM;
    for (int i = lane; i < H_DIM; i += 64) {
        float xv = x[i];
#pragma unroll
        for (int e = 0; e < NE; ++e) acc[e] += xv * gw[e * H_DIM + i];
    }
#pragma unroll
    for (int e = 0; e < NE; ++e)
        for (int off = 32; off > 0; off >>= 1) acc[e] += __shfl_xor(acc[e], off);
    if (lane == 0) {
        int i1 = 0; float l1 = acc[0];
#pragma unroll
        for (int e = 1; e < NE; ++e) if (acc[e] > l1) { l1 = acc[e]; i1 = e; }
        int i2 = -1; float l2 = -1e30f;
#pragma unroll
        for (int e = 0; e < NE; ++e) if (e != i1 && acc[e] > l2) { l2 = acc[e]; i2 = e; }
        float aa = __expf(l2 - l1);
        float s = 1.f / (1.f + aa);
        re[t * 2] = i1; re[t * 2 + 1] = i2;
        rw[t * 2] = s;  rw[t * 2 + 1] = aa * s;
        atomicAdd(&counts[i1], 1);
        atomicAdd(&counts[i2], 1);
    }
}

__global__ void scan_kernel(int* __restrict__ meta) {
    if (threadIdx.x == 0) {
        int s = 0;
        for (int e = 0; e < NE; ++e) { meta[8 + e] = s; meta[16 + e] = s; s += meta[e]; }
    }
}

__global__ void place_kernel(const int* __restrict__ re, const float* __restrict__ rw,
                             int* __restrict__ cursor, int* __restrict__ btok,
                             float* __restrict__ bwv) {
    int t = blockIdx.x * 256 + threadIdx.x;
    if (t >= T_TOK) return;
#pragma unroll
    for (int s = 0; s < 2; ++s) {
        int e = re[t * 2 + s];
        int p = atomicAdd(&cursor[e], 1);
        btok[p] = t;
        bwv[p] = rw[t * 2 + s];
    }
}

// Panel-pinned XCD decode: panel P = sg*8 + (id&7) stays on XCD id%8; the
// 32 by-blocks of one panel are contiguous ids on that XCD.
__device__ __forceinline__ void decode_panel(int id, int npx, int e_arg,
                                             int& e, int& bx, int& by) {
    int sg  = id >> 8;          // super-group: 8 panels x 32 by = 256 blocks
    int rem = id & 255;
    by = rem >> 3;
    int P = sg * 8 + (rem & 7);
    if (e_arg >= 0) { e = e_arg; bx = P; }
    else            { e = P / npx; bx = P % npx; }
}

// ---------------- GEMM1: h = silu(X@Wg^T) * (X@Wu^T) ----------------
// BM=128 tokens x 64 h-cols (g+u pair), BK=64, 512 thr / 8 waves (4m x 2n),
// wave = 32 rows x 32 cols of both g and u. Single-buffer LDS, reg prefetch.
// Per-thread staging halved vs R3 to stay under the VGPR=128 occupancy cliff.
__global__ __launch_bounds__(512) void gemm1_kernel(
    const float* __restrict__ w13, const f16* __restrict__ hsb, f16* __restrict__ hb,
    const int* __restrict__ counts, const int* __restrict__ offs,
    const int* __restrict__ btok, int e_arg, int global_h)
{
    int e, bx, by;
    decode_panel(blockIdx.x, 88, e_arg, e, bx, by);
    const int n_e = counts[e];
    if (by * 128 >= n_e) return;
    const int boff = offs[e];
    const float* We = w13 + (size_t)e * (2 * I_DIM) * H_DIM;

    const int tid = threadIdx.x;
    const int lane = tid & 63;
    const int wid = tid >> 6;           // 0..7
    const int wm = wid >> 1, wn = wid & 1;

    __shared__ f16 As[128 * 64];   // 16 KB, 128B rows
    __shared__ f16 Bg[64 * 64];    // 8 KB
    __shared__ f16 Bu[64 * 64];    // 8 KB
    char* AsB = (char*)As; char* BgB = (char*)Bg; char* BuB = (char*)Bu;

    // A: 2 chunks of 16B per thread. chunk c = i*512+tid: row c>>3, slot c&7
    const f16* gA[2];
    int awadr[2];
#pragma unroll
    for (int i = 0; i < 2; ++i) {
        int c = i * 512 + tid;
        int r = c >> 3;
        int s = c & 7;
        int idx = by * 128 + r;
        idx = idx < n_e ? idx : n_e - 1;
        int tok = btok[boff + idx];
        gA[i] = hsb + (size_t)tok * H_DIM + s * 8;
        awadr[i] = r * 128 + swzk(r, s * 16);
    }
    // B: per matrix 2 float4/thread. chunk c = j*512+tid: row c>>4, quad c&15
    const float* gBg[2]; const float* gBu[2];
    int bwadr[2];
#pragma unroll
    for (int j = 0; j < 2; ++j) {
        int c = j * 512 + tid;
        int r = c >> 4;
        int k4 = c & 15;
        gBg[j] = We + (size_t)(bx * 64 + r) * H_DIM + k4 * 4;
        gBu[j] = We + (size_t)(I_DIM + bx * 64 + r) * H_DIM + k4 * 4;
        bwadr[j] = r * 128 + swzk(r, k4 * 8);
    }

    f32x4 accg[2][2], accu[2][2];
#pragma unroll
    for (int m = 0; m < 2; ++m)
#pragma unroll
        for (int n = 0; n < 2; ++n) { accg[m][n] = (f32x4)0.f; accu[m][n] = (f32x4)0.f; }

    const int NT = H_DIM / 64;   // 32

    f16x8 aR[2]; float4 gR[2], uR[2];
#pragma unroll
    for (int i = 0; i < 2; ++i) {
        aR[i] = *(const f16x8*)(gA[i]);
        gR[i] = *(const float4*)(gBg[i]);
        uR[i] = *(const float4*)(gBu[i]);
    }

#pragma unroll 1
    for (int kt = 0; kt < NT; ++kt) {
        __syncthreads();
#pragma unroll
        for (int i = 0; i < 2; ++i) {
            *(f16x8*)(AsB + awadr[i]) = aR[i];
            *(f16x4*)(BgB + bwadr[i]) = cvt4(gR[i]);
            *(f16x4*)(BuB + bwadr[i]) = cvt4(uR[i]);
        }
        __syncthreads();
        if (kt + 1 < NT) {
            int k0 = (kt + 1) * 64;
#pragma unroll
            for (int i = 0; i < 2; ++i) {
                aR[i] = *(const f16x8*)(gA[i] + k0);
                gR[i] = *(const float4*)(gBg[i] + k0);
                uR[i] = *(const float4*)(gBu[i] + k0);
            }
        }
#pragma unroll
        for (int kh = 0; kh < 2; ++kh) {
            f16x8 a[2], bg[2], bu[2];
            const int kb = kh * 64 + (lane >> 4) * 16;
#pragma unroll
            for (int m = 0; m < 2; ++m) {
                int r = wm * 32 + m * 16 + (lane & 15);
                a[m] = *(const f16x8*)(AsB + r * 128 + swzk(r, kb));
            }
#pragma unroll
            for (int n = 0; n < 2; ++n) {
                int r = wn * 32 + n * 16 + (lane & 15);
                bg[n] = *(const f16x8*)(BgB + r * 128 + swzk(r, kb));
                bu[n] = *(const f16x8*)(BuB + r * 128 + swzk(r, kb));
            }
#pragma unroll
            for (int m = 0; m < 2; ++m)
#pragma unroll
                for (int n = 0; n < 2; ++n) {
                    accg[m][n] = __builtin_amdgcn_mfma_f32_16x16x32_f16(a[m], bg[n], accg[m][n], 0, 0, 0);
                    accu[m][n] = __builtin_amdgcn_mfma_f32_16x16x32_f16(a[m], bu[n], accu[m][n], 0, 0, 0);
                }
        }
    }

    // epilogue: silu(g)*u -> f16 h
    const int hbase = (global_h ? boff : 0) + by * 128;
#pragma unroll
    for (int m = 0; m < 2; ++m) {
        int rl0 = wm * 32 + m * 16 + ((lane >> 4) << 2);
#pragma unroll
        for (int r = 0; r < 4; ++r) {
            int rl = rl0 + r;
            if (by * 128 + rl < n_e) {
#pragma unroll
                for (int n = 0; n < 2; ++n) {
                    float g = accg[m][n][r];
                    float u = accu[m][n][r];
                    float h = g / (1.f + __expf(-g)) * u;
                    hb[(size_t)(hbase + rl) * I_DIM + bx * 64 + wn * 32 + n * 16 + (lane & 15)] = (f16)h;
                }
            }
        }
    }
}

// ---------------- GEMM2: out[tok] += w * (h @ w2^T) ----------------
// BM=128 x BN=128, BK=64, 512 thr / 8 waves (4m x 2n), wave 32x64.
__global__ __launch_bounds__(512) void gemm2_kernel(
    const float* __restrict__ w2, const f16* __restrict__ hb, float* __restrict__ out,
    const int* __restrict__ counts, const int* __restrict__ offs,
    const int* __restrict__ btok, const float* __restrict__ bwv, int e_arg, int global_h)
{
    int e, bx, by;
    decode_panel(blockIdx.x, 16, e_arg, e, bx, by);
    const int n_e = counts[e];
    if (by * 128 >= n_e) return;
    const int boff = offs[e];
    const float* We = w2 + (size_t)e * H_DIM * I_DIM;

    const int tid = threadIdx.x;
    const int lane = tid & 63;
    const int wid = tid >> 6;
    const int wm = wid >> 1, wn = wid & 1;

    __shared__ f16 As[128 * 64];   // 16 KB
    __shared__ f16 Bs[128 * 64];   // 16 KB
    char* AsB = (char*)As; char* BsB = (char*)Bs;

    const int hbase = (global_h ? boff : 0) + by * 128;
    const f16* gA[2];
    int awadr[2];
#pragma unroll
    for (int i = 0; i < 2; ++i) {
        int c = i * 512 + tid;
        int r = c >> 3;
        int s = c & 7;
        gA[i] = hb + (size_t)(hbase + r) * I_DIM + s * 8;
        awadr[i] = r * 128 + swzk(r, s * 16);
    }
    const float* gB[4];
    int bwadr[4];
#pragma unroll
    for (int j = 0; j < 4; ++j) {
        int c = j * 512 + tid;
        int r = c >> 4;          // 0..127
        int k4 = c & 15;
        gB[j] = We + (size_t)(bx * 128 + r) * I_DIM + k4 * 4;
        bwadr[j] = r * 128 + swzk(r, k4 * 8);
    }

    f32x4 acc[2][4];
#pragma unroll
    for (int m = 0; m < 2; ++m)
#pragma unroll
        for (int n = 0; n < 4; ++n) acc[m][n] = (f32x4)0.f;

    const int NT = I_DIM / 64;   // 88

    f16x8 aR[2]; float4 bR[4];
#pragma unroll
    for (int i = 0; i < 2; ++i) aR[i] = *(const f16x8*)(gA[i]);
#pragma unroll
    for (int j = 0; j < 4; ++j) bR[j] = *(const float4*)(gB[j]);

#pragma unroll 1
    for (int kt = 0; kt < NT; ++kt) {
        __syncthreads();
#pragma unroll
        for (int i = 0; i < 2; ++i) *(f16x8*)(AsB + awadr[i]) = aR[i];
#pragma unroll
        for (int j = 0; j < 4; ++j) *(f16x4*)(BsB + bwadr[j]) = cvt4(bR[j]);
        __syncthreads();
        if (kt + 1 < NT) {
            int k0 = (kt + 1) * 64;
#pragma unroll
            for (int i = 0; i < 2; ++i) aR[i] = *(const f16x8*)(gA[i] + k0);
#pragma unroll
            for (int j = 0; j < 4; ++j) bR[j] = *(const float4*)(gB[j] + k0);
        }
#pragma unroll
        for (int kh = 0; kh < 2; ++kh) {
            f16x8 a[2], b[4];
            const int kb = kh * 64 + (lane >> 4) * 16;
#pragma unroll
            for (int m = 0; m < 2; ++m) {
                int r = wm * 32 + m * 16 + (lane & 15);
                a[m] = *(const f16x8*)(AsB + r * 128 + swzk(r, kb));
            }
#pragma unroll
            for (int n = 0; n < 4; ++n) {
                int r = wn * 64 + n * 16 + (lane & 15);
                b[n] = *(const f16x8*)(BsB + r * 128 + swzk(r, kb));
            }
#pragma unroll
            for (int m = 0; m < 2; ++m)
#pragma unroll
                for (int n = 0; n < 4; ++n)
                    acc[m][n] = __builtin_amdgcn_mfma_f32_16x16x32_f16(a[m], b[n], acc[m][n], 0, 0, 0);
        }
    }

    // epilogue: weighted scatter-add
#pragma unroll
    for (int m = 0; m < 2; ++m) {
        int rl0 = wm * 32 + m * 16 + ((lane >> 4) << 2);
#pragma unroll
        for (int r = 0; r < 4; ++r) {
            int rl = rl0 + r;
            if (by * 128 + rl < n_e) {
                int p = boff + by * 128 + rl;
                int tok = btok[p];
                float w = bwv[p];
#pragma unroll
                for (int n = 0; n < 4; ++n)
                    atomicAdd(&out[(size_t)tok * H_DIM + bx * 128 + wn * 64 + n * 16 + (lane & 15)],
                              w * acc[m][n][r]);
            }
        }
    }
}

extern "C" void kernel_launch(void* const* d_in, const int* in_sizes, int n_in,
                              void* d_out, int out_size, void* d_ws, size_t ws_size,
                              hipStream_t stream) {
    const float* hs  = (const float*)d_in[0];
    const float* gw  = (const float*)d_in[1];
    const float* w13 = (const float*)d_in[2];
    const float* w2  = (const float*)d_in[3];
    float* out = (float*)d_out;

    char* ws = (char*)d_ws;
    int*   meta = (int*)(ws + OFF_META);
    int*   btok = (int*)(ws + OFF_BTOK);
    float* bwv  = (float*)(ws + OFF_BW);
    int*   re   = (int*)(ws + OFF_RE);
    float* rw   = (float*)(ws + OFF_RW);
    f16*   hsb  = (f16*)(ws + OFF_HSB);
    f16*   hb   = (f16*)(ws + OFF_HB);

    hipMemsetAsync(d_out, 0, (size_t)T_TOK * H_DIM * 4, stream);
    hipMemsetAsync(meta, 0, 256, stream);

    cvt_hs_kernel<<<(T_TOK * H_DIM) / (256 * 8), 256, 0, stream>>>(hs, hsb);
    gate_kernel<<<T_TOK / 4, 256, 0, stream>>>(hs, gw, re, rw, meta);
    scan_kernel<<<1, 64, 0, stream>>>(meta);
    place_kernel<<<T_TOK / 256, 256, 0, stream>>>(re, rw, meta + 16, btok, bwv);

    size_t need_allpairs = OFF_HB + (size_t)(2 * T_TOK + 128) * I_DIM * 2;
    if (ws_size >= need_allpairs) {
        // panels: gemm1 = 8*88 = 704, gemm2 = 8*16 = 128; 32 by-blocks per panel
        gemm1_kernel<<<704 * 32, 512, 0, stream>>>(w13, hsb, hb, meta, meta + 8, btok, -1, 1);
        gemm2_kernel<<<128 * 32, 512, 0, stream>>>(w2, hb, out, meta, meta + 8, btok, bwv, -1, 1);
    } else {
        for (int e = 0; e < NE; ++e) {
            gemm1_kernel<<<88 * 32, 512, 0, stream>>>(w13, hsb, hb, meta, meta + 8, btok, e, 0);
            gemm2_kernel<<<16 * 32, 512, 0, stream>>>(w2, hb, out, meta, meta + 8, btok, bwv, e, 0);
        }
    }
}